// Round 11
// baseline (105.700 us; speedup 1.0000x reference)
//
#include <hip/hip_runtime.h>
#include <hip/hip_bf16.h>

typedef __bf16 bf16x8 __attribute__((ext_vector_type(8)));
typedef float f32x4 __attribute__((ext_vector_type(4)));
typedef unsigned short us8 __attribute__((ext_vector_type(8)));

#define MFMA16 __builtin_amdgcn_mfma_f32_16x16x32_bf16

__device__ __forceinline__ unsigned short f2bf(float f) {
    unsigned int u = __float_as_uint(f);
    u += 0x7fffu + ((u >> 16) & 1u);   // round-to-nearest-even
    return (unsigned short)(u >> 16);
}

// ============ Pass 1 (fused): pack A' = [x | h] along K' and B-hat panels ====
// Frag = 1024 B = 16 rows x 32 k (lane=(kk>>3)*16+row, 8 contig k per lane).
// A': frag index = mb*32 + kb'  (kb' = kb for x, 16+kb for h), mb 0..511.
// B-hat: 3 buffers (R,U,C) of [nb 0..31][kb' 0..31] frags; kb'<16 from Wx_*,
//        kb'>=16 from Wh_*.
__global__ void cvt_all_kernel(const float* __restrict__ x, const float* __restrict__ h,
                               unsigned short* __restrict__ AP,
                               const float* __restrict__ W0, const float* __restrict__ W1,
                               const float* __restrict__ W2, const float* __restrict__ W3,
                               const float* __restrict__ W4, const float* __restrict__ W5,
                               unsigned short* __restrict__ WP) {
    if (blockIdx.x < 4096) {                         // x,h -> A'
        int c = blockIdx.x * 256 + threadIdx.x;      // 0 .. 2^20-1
        int ih = c >> 19;
        const float* src = ih ? h : x;
        int c2 = c & 524287;
        int mb = c2 >> 10, kb = (c2 >> 6) & 15, lane = c2 & 63;
        int r = lane & 15, ko = lane >> 4;
        const float* p = src + (size_t)(mb * 16 + r) * 512 + kb * 32 + ko * 8;
        float4 v0 = *(const float4*)p;
        float4 v1 = *(const float4*)(p + 4);
        us8 o = { f2bf(v0.x), f2bf(v0.y), f2bf(v0.z), f2bf(v0.w),
                  f2bf(v1.x), f2bf(v1.y), f2bf(v1.z), f2bf(v1.w) };
        *((us8*)AP + ((size_t)(mb * 32 + kb + ih * 16) << 6) + lane) = o;
    } else {                                          // weights -> B-hat
        int c = (blockIdx.x - 4096) * 256 + threadIdx.x;   // 0..196607
        int s = c >> 16, c2 = c & 65535;
        int frag = c2 >> 6, lane = c2 & 63;
        int nb = frag >> 5, kbp = frag & 31;
        const float* Wsrc;
        int kb;
        if (kbp < 16) { kb = kbp;      Wsrc = (s == 0) ? W0 : (s == 1) ? W2 : W4; }
        else          { kb = kbp - 16; Wsrc = (s == 0) ? W1 : (s == 1) ? W3 : W5; }
        int cc = lane & 15, ko = lane >> 4;
        int kbase = kb * 32 + ko * 8;
        us8 o;
#pragma unroll
        for (int e = 0; e < 8; ++e)
            o[e] = f2bf(Wsrc[(size_t)(kbase + e) * 512 + nb * 16 + cc]);
        *((us8*)WP + c) = o;
    }
}

// ============ Pass 2: max-TLP fused GEMM + AUGRU epilogue ============
// Latency-bound regime (rounds 2-10: all pipes <20%, racy variant ran 7us)
// -> attack with THREAD-LEVEL PARALLELISM, not scheduling.
// Wave tile 32r x 16c (acc 8 x f32x4 = 32 VGPR). Block = 4 waves, 1M x 4N
// (waves share A rows -> L1/L2 dedup). Grid 2048 = 8 blocks/CU.
// ZERO LDS, ZERO barriers, ZERO inline asm. Double-set register rotate.
// __launch_bounds__(256,6): target 6 waves/SIMD = 3x previous concurrency.
__global__ __launch_bounds__(256, 6) void augru_mm(
    const unsigned short* __restrict__ AP_,
    const unsigned short* __restrict__ WP_,   // 3 x 1 MiB (R,U,C)
    const float* __restrict__ b_r, const float* __restrict__ b_u, const float* __restrict__ b_h,
    const float* __restrict__ att, const float* __restrict__ h32,
    float* __restrict__ out) {
    const unsigned char* __restrict__ APb = (const unsigned char*)AP_;
    const unsigned char* __restrict__ WPb = (const unsigned char*)WP_;

    const int t0 = threadIdx.x, wv = t0 >> 6, lane = t0 & 63;
    const int laneoff = lane * 16;

    // bijective XCD swizzle: XCD x owns Wid in [256x,256x+256) -> 32 m-panels
    // (32 rows each) -> 2 MB A-slice per XCD, L2-resident.
    const int bid = blockIdx.x;               // 0..2047
    const int Wid = (bid & 7) * 256 + (bid >> 3);
    const int mblk = Wid >> 3;                // 0..255 (32-row panel)
    const int nblk16 = (Wid & 7) * 4 + wv;    // 0..31 (16-col tile per wave)

    f32x4 accR[2] = {}, accU[2] = {}, accXH[2] = {}, accHH[2] = {};

    const unsigned char* __restrict__ pAl = APb + laneoff;
    const unsigned char* __restrict__ pBl = WPb + laneoff;
    size_t Aoff[2], Boff[3];
#pragma unroll
    for (int mf = 0; mf < 2; ++mf)
        Aoff[mf] = ((size_t)((mblk * 2 + mf) * 32)) << 10;
#pragma unroll
    for (int s = 0; s < 3; ++s)
        Boff[s] = (size_t)s * 1048576 + (((size_t)(nblk16 * 32)) << 10);

    bf16x8 a0[2], a1[2], b0[3], b1[3];

#define LOADSET(S, T) { \
    _Pragma("unroll") for (int mf = 0; mf < 2; ++mf) \
        a##S[mf] = *(const bf16x8*)(pAl + Aoff[mf] + ((size_t)(T) << 10)); \
    _Pragma("unroll") for (int s = 0; s < 3; ++s) \
        b##S[s] = *(const bf16x8*)(pBl + Boff[s] + ((size_t)(T) << 10)); }

#define MFMASET(S, ACCC) { \
    __builtin_amdgcn_s_setprio(1); \
    _Pragma("unroll") for (int mf = 0; mf < 2; ++mf) { \
        accR[mf] = MFMA16(a##S[mf], b##S[0], accR[mf], 0, 0, 0); \
        accU[mf] = MFMA16(a##S[mf], b##S[1], accU[mf], 0, 0, 0); \
        ACCC[mf] = MFMA16(a##S[mf], b##S[2], ACCC[mf], 0, 0, 0); } \
    __builtin_amdgcn_s_setprio(0); }

    LOADSET(0, 0)
#pragma unroll
    for (int T = 0; T < 16; T += 2) {         // tiles 0..15: x-half -> accXH
        LOADSET(1, T + 1)
        MFMASET(0, accXH)
        LOADSET(0, T + 2)                     // tile 16 load belongs to h-half
        MFMASET(1, accXH)
    }
#pragma unroll
    for (int T = 16; T < 30; T += 2) {        // tiles 16..29: h-half -> accHH
        LOADSET(1, T + 1)
        MFMASET(0, accHH)
        LOADSET(0, T + 2)
        MFMASET(1, accHH)
    }
    LOADSET(1, 31)                            // tiles 30,31
    MFMASET(0, accHH)
    MFMASET(1, accHH)

    // epilogue: C/D layout col=lane&15, row=(lane>>4)*4+reg  [m89-verified]
    const int lr = lane & 15, lg = lane >> 4;
    const int col = nblk16 * 16 + lr;
    const float br = b_r[col], bu = b_u[col], bh = b_h[col];
#pragma unroll
    for (int mf = 0; mf < 2; ++mf) {
        const int rowb = mblk * 32 + mf * 16 + lg * 4;
#pragma unroll
        for (int q = 0; q < 4; ++q) {
            const int row = rowb + q;
            float r = 1.f / (1.f + __expf(-(accR[mf][q] + br)));
            float u = 1.f / (1.f + __expf(-(accU[mf][q] + bu)));
            float ph = accXH[mf][q] + bh + r * accHH[mf][q];
            ph = fminf(fmaxf(ph, -15.f), 15.f);
            float e = __expf(2.f * ph);
            float cal = (e - 1.f) / (e + 1.f);
            float hv = h32[(size_t)row * 512 + col];
            float ua = att[row] * u;
            out[(size_t)row * 512 + col] = fmaf(ua, cal - hv, hv);
        }
    }
#undef LOADSET
#undef MFMASET
}

extern "C" void kernel_launch(void* const* d_in, const int* in_sizes, int n_in,
                              void* d_out, int out_size, void* d_ws, size_t ws_size,
                              hipStream_t stream) {
    const float* x    = (const float*)d_in[0];
    const float* h    = (const float*)d_in[1];
    const float* att  = (const float*)d_in[2];
    const float* Wx_r = (const float*)d_in[3];
    const float* b_r  = (const float*)d_in[4];
    const float* Wh_r = (const float*)d_in[5];
    const float* Wx_u = (const float*)d_in[6];
    const float* b_u  = (const float*)d_in[7];
    const float* Wh_u = (const float*)d_in[8];
    const float* Wx_h = (const float*)d_in[9];
    const float* b_h  = (const float*)d_in[10];
    const float* Wh_h = (const float*)d_in[11];
    float* out = (float*)d_out;

    unsigned short* AP = (unsigned short*)d_ws;   // 16 MiB packed [x|h]
    unsigned short* WP = AP + 8388608;            //  3 MiB packed B-hat (R,U,C)

    cvt_all_kernel<<<4864, 256, 0, stream>>>(x, h, AP,
        Wx_r, Wh_r, Wx_u, Wh_u, Wx_h, Wh_h, WP);
    augru_mm<<<2048, 256, 0, stream>>>(AP, WP, b_r, b_u, b_h, att, h, out);
}

// Round 12
// 82.546 us; speedup vs baseline: 1.2805x; 1.2805x over previous
//
#include <hip/hip_runtime.h>
#include <hip/hip_bf16.h>

typedef __bf16 bf16x8 __attribute__((ext_vector_type(8)));
typedef float f32x4 __attribute__((ext_vector_type(4)));
typedef unsigned short us8 __attribute__((ext_vector_type(8)));

#define MFMA16 __builtin_amdgcn_mfma_f32_16x16x32_bf16

__device__ __forceinline__ unsigned short f2bf(float f) {
    unsigned int u = __float_as_uint(f);
    u += 0x7fffu + ((u >> 16) & 1u);   // round-to-nearest-even
    return (unsigned short)(u >> 16);
}

// ============ Pass 1 (fused): pack A' = [x | h] along K' and B-hat panels ====
// Frag = 1024 B = 16 rows x 32 k (lane=(kk>>3)*16+row, 8 contig k per lane).
// A': frag index = mb*32 + kb'  (kb' = kb for x, 16+kb for h), mb 0..511.
// B-hat: 3 buffers (R,U,C) of [nb 0..31][kb' 0..31] frags; kb'<16 from Wx_*,
//        kb'>=16 from Wh_*.
__global__ void cvt_all_kernel(const float* __restrict__ x, const float* __restrict__ h,
                               unsigned short* __restrict__ AP,
                               const float* __restrict__ W0, const float* __restrict__ W1,
                               const float* __restrict__ W2, const float* __restrict__ W3,
                               const float* __restrict__ W4, const float* __restrict__ W5,
                               unsigned short* __restrict__ WP) {
    if (blockIdx.x < 4096) {                         // x,h -> A'
        int c = blockIdx.x * 256 + threadIdx.x;      // 0 .. 2^20-1
        int ih = c >> 19;
        const float* src = ih ? h : x;
        int c2 = c & 524287;
        int mb = c2 >> 10, kb = (c2 >> 6) & 15, lane = c2 & 63;
        int r = lane & 15, ko = lane >> 4;
        const float* p = src + (size_t)(mb * 16 + r) * 512 + kb * 32 + ko * 8;
        float4 v0 = *(const float4*)p;
        float4 v1 = *(const float4*)(p + 4);
        us8 o = { f2bf(v0.x), f2bf(v0.y), f2bf(v0.z), f2bf(v0.w),
                  f2bf(v1.x), f2bf(v1.y), f2bf(v1.z), f2bf(v1.w) };
        *((us8*)AP + ((size_t)(mb * 32 + kb + ih * 16) << 6) + lane) = o;
    } else {                                          // weights -> B-hat
        int c = (blockIdx.x - 4096) * 256 + threadIdx.x;   // 0..196607
        int s = c >> 16, c2 = c & 65535;
        int frag = c2 >> 6, lane = c2 & 63;
        int nb = frag >> 5, kbp = frag & 31;
        const float* Wsrc;
        int kb;
        if (kbp < 16) { kb = kbp;      Wsrc = (s == 0) ? W0 : (s == 1) ? W2 : W4; }
        else          { kb = kbp - 16; Wsrc = (s == 0) ? W1 : (s == 1) ? W3 : W5; }
        int cc = lane & 15, ko = lane >> 4;
        int kbase = kb * 32 + ko * 8;
        us8 o;
#pragma unroll
        for (int e = 0; e < 8; ++e)
            o[e] = f2bf(Wsrc[(size_t)(kbase + e) * 512 + nb * 16 + cc]);
        *((us8*)WP + c) = o;
    }
}

// ============ Pass 2: low-vmem-density pure-VGPR GEMM + AUGRU epilogue ======
// Theory: per-CU vmem-instruction throughput is the binding resource (V2
// racy-fast = 7 instr/wave/BK64; all slow variants >= 16). This kernel:
// 7 vmem instr per wave per BK32 (4 A + 3 B) vs 12 MFMA; 3-deep static
// rotation (full unroll, slot = T%3 compile-time); no LDS, no barriers,
// no inline asm. Block = 4 waves sharing IDENTICAL A addresses (L1 dedup),
// wave tile 64r x 16c, block 64r x 64c. Grid 1024 = 4 blocks/CU; m-grouped
// XCD swizzle keeps per-XCD L2 set to A 2MB + B 3MB (fits 4MB L2).
__global__ __launch_bounds__(256, 3) void augru_mm(
    const unsigned short* __restrict__ AP_,
    const unsigned short* __restrict__ WP_,   // 3 x 1 MiB (R,U,C)
    const float* __restrict__ b_r, const float* __restrict__ b_u, const float* __restrict__ b_h,
    const float* __restrict__ att, const float* __restrict__ h32,
    float* __restrict__ out) {
    const unsigned char* __restrict__ APb = (const unsigned char*)AP_;
    const unsigned char* __restrict__ WPb = (const unsigned char*)WP_;

    const int t0 = threadIdx.x, wv = t0 >> 6, lane = t0 & 63;
    const int laneoff = lane * 16;

    // bijective XCD swizzle: XCD x owns Wid [128x,128x+128) = 16 m-panels x 8 n
    const int bid = blockIdx.x;               // 0..1023
    const int Wid = (bid & 7) * 128 + (bid >> 3);
    const int mblk = Wid >> 3;                // 0..127 (64-row panel)
    const int nblk = Wid & 7;                 // 0..7   (64-col panel)
    const int nb = nblk * 4 + wv;             // 16-col index 0..31 (per wave)

    f32x4 accR[4] = {}, accU[4] = {}, accXH[4] = {}, accHH[4] = {};

    const unsigned char* __restrict__ pA[4];
    const unsigned char* __restrict__ pB[3];
#pragma unroll
    for (int mf = 0; mf < 4; ++mf)
        pA[mf] = APb + (((size_t)((mblk * 4 + mf) * 32)) << 10) + laneoff;
#pragma unroll
    for (int s = 0; s < 3; ++s)
        pB[s] = WPb + (size_t)s * 1048576 + (((size_t)(nb * 32)) << 10) + laneoff;

    bf16x8 sa[3][4], sb[3][3];                // 3-deep rotation; static idx only

#define LOADT(T) { \
    _Pragma("unroll") for (int mf = 0; mf < 4; ++mf) \
        sa[(T) % 3][mf] = *(const bf16x8*)(pA[mf] + ((size_t)(T) << 10)); \
    _Pragma("unroll") for (int s = 0; s < 3; ++s) \
        sb[(T) % 3][s] = *(const bf16x8*)(pB[s] + ((size_t)(T) << 10)); }

    LOADT(0) LOADT(1) LOADT(2)

#pragma unroll
    for (int T = 0; T < 32; ++T) {
        const int sl = T % 3;                 // compile-time after unroll
#pragma unroll
        for (int mf = 0; mf < 4; ++mf) {
            accR[mf] = MFMA16(sa[sl][mf], sb[sl][0], accR[mf], 0, 0, 0);
            accU[mf] = MFMA16(sa[sl][mf], sb[sl][1], accU[mf], 0, 0, 0);
            if (T < 16) accXH[mf] = MFMA16(sa[sl][mf], sb[sl][2], accXH[mf], 0, 0, 0);
            else        accHH[mf] = MFMA16(sa[sl][mf], sb[sl][2], accHH[mf], 0, 0, 0);
        }
        if (T + 3 < 32) LOADT(T + 3)          // refill same slot, 3 tiles ahead
    }

    // epilogue: C/D layout col=lane&15, row=(lane>>4)*4+reg  [m89-verified]
    const int lr = lane & 15, lg = lane >> 4;
    const int col = nb * 16 + lr;
    const float br = b_r[col], bu = b_u[col], bh = b_h[col];
#pragma unroll
    for (int mf = 0; mf < 4; ++mf) {
        const int rowb = mblk * 64 + mf * 16 + lg * 4;
#pragma unroll
        for (int q = 0; q < 4; ++q) {
            const int row = rowb + q;
            float r = 1.f / (1.f + __expf(-(accR[mf][q] + br)));
            float u = 1.f / (1.f + __expf(-(accU[mf][q] + bu)));
            float ph = accXH[mf][q] + bh + r * accHH[mf][q];
            ph = fminf(fmaxf(ph, -15.f), 15.f);
            float e = __expf(2.f * ph);
            float cal = (e - 1.f) / (e + 1.f);
            float hv = h32[(size_t)row * 512 + col];
            float ua = att[row] * u;
            out[(size_t)row * 512 + col] = fmaf(ua, cal - hv, hv);
        }
    }
#undef LOADT
}

extern "C" void kernel_launch(void* const* d_in, const int* in_sizes, int n_in,
                              void* d_out, int out_size, void* d_ws, size_t ws_size,
                              hipStream_t stream) {
    const float* x    = (const float*)d_in[0];
    const float* h    = (const float*)d_in[1];
    const float* att  = (const float*)d_in[2];
    const float* Wx_r = (const float*)d_in[3];
    const float* b_r  = (const float*)d_in[4];
    const float* Wh_r = (const float*)d_in[5];
    const float* Wx_u = (const float*)d_in[6];
    const float* b_u  = (const float*)d_in[7];
    const float* Wh_u = (const float*)d_in[8];
    const float* Wx_h = (const float*)d_in[9];
    const float* b_h  = (const float*)d_in[10];
    const float* Wh_h = (const float*)d_in[11];
    float* out = (float*)d_out;

    unsigned short* AP = (unsigned short*)d_ws;   // 16 MiB packed [x|h]
    unsigned short* WP = AP + 8388608;            //  3 MiB packed B-hat (R,U,C)

    cvt_all_kernel<<<4864, 256, 0, stream>>>(x, h, AP,
        Wx_r, Wh_r, Wx_u, Wh_u, Wx_h, Wh_h, WP);
    augru_mm<<<1024, 256, 0, stream>>>(AP, WP, b_r, b_u, b_h, att, h, out);
}

// Round 13
// 56.252 us; speedup vs baseline: 1.8790x; 1.4674x over previous
//
#include <hip/hip_runtime.h>
#include <hip/hip_bf16.h>

typedef __bf16 bf16x8 __attribute__((ext_vector_type(8)));
typedef float f32x4 __attribute__((ext_vector_type(4)));
typedef unsigned short us8 __attribute__((ext_vector_type(8)));

#define MFMA16 __builtin_amdgcn_mfma_f32_16x16x32_bf16

__device__ __forceinline__ unsigned short f2bf(float f) {
    unsigned int u = __float_as_uint(f);
    u += 0x7fffu + ((u >> 16) & 1u);   // round-to-nearest-even
    return (unsigned short)(u >> 16);
}

__device__ __forceinline__ void gload_lds16(const void* g, void* l) {
    __builtin_amdgcn_global_load_lds(
        (const __attribute__((address_space(1))) unsigned int*)g,
        (__attribute__((address_space(3))) unsigned int*)l, 16, 0, 0);
}

// ============ Pass 1 (fused): pack A' = [x | h] along K' and B-hat panels ====
// Frag = 1024 B = 16 rows x 32 k (lane=(kk>>3)*16+row, 8 contig k per lane).
// A': frag index = mb*32 + kb'  (kb' = kb for x, 16+kb for h), mb 0..511.
// B-hat: 3 buffers (R,U,C) of [nb 0..31][kb' 0..31] frags; kb'<16 from Wx_*,
//        kb'>=16 from Wh_*.
__global__ void cvt_all_kernel(const float* __restrict__ x, const float* __restrict__ h,
                               unsigned short* __restrict__ AP,
                               const float* __restrict__ W0, const float* __restrict__ W1,
                               const float* __restrict__ W2, const float* __restrict__ W3,
                               const float* __restrict__ W4, const float* __restrict__ W5,
                               unsigned short* __restrict__ WP) {
    if (blockIdx.x < 4096) {                         // x,h -> A'
        int c = blockIdx.x * 256 + threadIdx.x;      // 0 .. 2^20-1
        int ih = c >> 19;
        const float* src = ih ? h : x;
        int c2 = c & 524287;
        int mb = c2 >> 10, kb = (c2 >> 6) & 15, lane = c2 & 63;
        int r = lane & 15, ko = lane >> 4;
        const float* p = src + (size_t)(mb * 16 + r) * 512 + kb * 32 + ko * 8;
        float4 v0 = *(const float4*)p;
        float4 v1 = *(const float4*)(p + 4);
        us8 o = { f2bf(v0.x), f2bf(v0.y), f2bf(v0.z), f2bf(v0.w),
                  f2bf(v1.x), f2bf(v1.y), f2bf(v1.z), f2bf(v1.w) };
        *((us8*)AP + ((size_t)(mb * 32 + kb + ih * 16) << 6) + lane) = o;
    } else {                                          // weights -> B-hat
        int c = (blockIdx.x - 4096) * 256 + threadIdx.x;   // 0..196607
        int s = c >> 16, c2 = c & 65535;
        int frag = c2 >> 6, lane = c2 & 63;
        int nb = frag >> 5, kbp = frag & 31;
        const float* Wsrc;
        int kb;
        if (kbp < 16) { kb = kbp;      Wsrc = (s == 0) ? W0 : (s == 1) ? W2 : W4; }
        else          { kb = kbp - 16; Wsrc = (s == 0) ? W1 : (s == 1) ? W3 : W5; }
        int cc = lane & 15, ko = lane >> 4;
        int kbase = kb * 32 + ko * 8;
        us8 o;
#pragma unroll
        for (int e = 0; e < 8; ++e)
            o[e] = f2bf(Wsrc[(size_t)(kbase + e) * 512 + nb * 16 + cc]);
        *((us8*)WP + c) = o;
    }
}

// ============ Pass 2: B-resident-LDS fused GEMM + AUGRU epilogue ============
// Requirements proven by rounds 2-12:
//   - NO per-tile barriers (convoy = 50us); exactly 3 __syncthreads total.
//   - B via LDS (one-time staged, read-only), A global->reg wave-private.
//   - Register budget fits the cap: acc 64 + A-slots 32 + pA 8 + misc ~118
//     under launch_bounds(512,4)'s 128 cap -> pipeline survives regalloc.
// Block: 512 thr = 8 waves x 64 rows, 16 cols. Grid 512 = 2 blocks/CU,
// 16 waves/CU. LDS 48KB = one K-half of B (3 sets x 16 frags x 1KB),
// restaged once at the K midpoint (= the accXH/accHH switch).
__global__ __launch_bounds__(512, 4) void augru_mm(
    const unsigned short* __restrict__ AP_,
    const unsigned short* __restrict__ WP_,   // 3 x 1 MiB (R,U,C)
    const float* __restrict__ b_r, const float* __restrict__ b_u, const float* __restrict__ b_h,
    const float* __restrict__ att, const float* __restrict__ h32,
    float* __restrict__ out) {
    __shared__ unsigned char sB[49152];       // [set 0..2][kbi 0..15][1KB]
    const unsigned char* __restrict__ APb = (const unsigned char*)AP_;
    const unsigned char* __restrict__ WPb = (const unsigned char*)WP_;

    const int t0 = threadIdx.x, wv = t0 >> 6, lane = t0 & 63;
    const int laneoff = lane * 16;

    // bijective XCD swizzle: XCD x owns Wid [64x,64x+64) = 2 m-panels x 32 n
    // -> per-XCD A slice 2 MB (L2-resident, 32-fold reuse across n-blocks).
    const int bid = blockIdx.x;               // 0..511
    const int Wid = (bid & 7) * 64 + (bid >> 3);
    const int mp = Wid >> 5;                  // m-panel 0..15 (512 rows)
    const int nb16 = Wid & 31;                // n-tile 0..31 (16 cols)

    f32x4 accR[4] = {}, accU[4] = {}, accXH[4] = {}, accHH[4] = {};

    // A: wave-private rows; mb16 = mp*32 + wv*4 + mf
    const unsigned char* __restrict__ pA[4];
#pragma unroll
    for (int mf = 0; mf < 4; ++mf)
        pA[mf] = APb + (((size_t)((mp * 32 + wv * 4 + mf) * 32)) << 10) + laneoff;

    // B staging: thread's wave stages frags f = wv + 8i (i=0..5) of the chunk
#define STAGE(c) { _Pragma("unroll") for (int i = 0; i < 6; ++i) { \
        int f = wv + 8 * i, s = f >> 4, kbi = f & 15; \
        gload_lds16(WPb + (size_t)s * 1048576 + \
                    (((size_t)(nb16 * 32 + (c) * 16 + kbi)) << 10) + laneoff, \
                    (unsigned char*)sB + (f << 10)); } }

#define LOADA(SL, T) { _Pragma("unroll") for (int mf = 0; mf < 4; ++mf) \
        SL[mf] = *(const bf16x8*)(pA[mf] + ((size_t)(T) << 10)); }

#define CONSUME(SL, T, ACCC) { \
    const int kbi_ = (T) & 15; \
    bf16x8 bR = *(const bf16x8*)(sB + (kbi_ << 10) + laneoff); \
    bf16x8 bU = *(const bf16x8*)(sB + 16384 + (kbi_ << 10) + laneoff); \
    bf16x8 bC = *(const bf16x8*)(sB + 32768 + (kbi_ << 10) + laneoff); \
    _Pragma("unroll") for (int mf = 0; mf < 4; ++mf) { \
        accR[mf] = MFMA16(SL[mf], bR, accR[mf], 0, 0, 0); \
        accU[mf] = MFMA16(SL[mf], bU, accU[mf], 0, 0, 0); \
        ACCC[mf] = MFMA16(SL[mf], bC, ACCC[mf], 0, 0, 0); } }

    bf16x8 sa0[4], sa1[4];

    STAGE(0)
    __syncthreads();                          // barrier 1: chunk-0 B ready
    LOADA(sa0, 0) LOADA(sa1, 1)

#pragma unroll
    for (int i = 0; i < 8; ++i) {             // tiles 0..15: x-half -> accXH
        const int T = 2 * i;
        CONSUME(sa0, T, accXH)     LOADA(sa0, T + 2)
        CONSUME(sa1, T + 1, accXH) LOADA(sa1, T + 3)
    }
    __syncthreads();                          // barrier 2: all done reading c0
    STAGE(1)
    __syncthreads();                          // barrier 3: chunk-1 B ready
#pragma unroll
    for (int i = 8; i < 16; ++i) {            // tiles 16..31: h-half -> accHH
        const int T = 2 * i;
        CONSUME(sa0, T, accHH)
        if (T + 2 < 32) LOADA(sa0, T + 2)
        CONSUME(sa1, T + 1, accHH)
        if (T + 3 < 32) LOADA(sa1, T + 3)
    }

    // epilogue: C/D layout col=lane&15, row=(lane>>4)*4+reg  [m89-verified]
    const int lr = lane & 15, lg = lane >> 4;
    const int col = nb16 * 16 + lr;
    const float br = b_r[col], bu = b_u[col], bh = b_h[col];
#pragma unroll
    for (int mf = 0; mf < 4; ++mf) {
        const int rowb = mp * 512 + wv * 64 + mf * 16 + lg * 4;
#pragma unroll
        for (int q = 0; q < 4; ++q) {
            const int row = rowb + q;
            float r = 1.f / (1.f + __expf(-(accR[mf][q] + br)));
            float u = 1.f / (1.f + __expf(-(accU[mf][q] + bu)));
            float ph = accXH[mf][q] + bh + r * accHH[mf][q];
            ph = fminf(fmaxf(ph, -15.f), 15.f);
            float e = __expf(2.f * ph);
            float cal = (e - 1.f) / (e + 1.f);
            float hv = h32[(size_t)row * 512 + col];
            float ua = att[row] * u;
            out[(size_t)row * 512 + col] = fmaf(ua, cal - hv, hv);
        }
    }
#undef STAGE
#undef LOADA
#undef CONSUME
}

extern "C" void kernel_launch(void* const* d_in, const int* in_sizes, int n_in,
                              void* d_out, int out_size, void* d_ws, size_t ws_size,
                              hipStream_t stream) {
    const float* x    = (const float*)d_in[0];
    const float* h    = (const float*)d_in[1];
    const float* att  = (const float*)d_in[2];
    const float* Wx_r = (const float*)d_in[3];
    const float* b_r  = (const float*)d_in[4];
    const float* Wh_r = (const float*)d_in[5];
    const float* Wx_u = (const float*)d_in[6];
    const float* b_u  = (const float*)d_in[7];
    const float* Wh_u = (const float*)d_in[8];
    const float* Wx_h = (const float*)d_in[9];
    const float* b_h  = (const float*)d_in[10];
    const float* Wh_h = (const float*)d_in[11];
    float* out = (float*)d_out;

    unsigned short* AP = (unsigned short*)d_ws;   // 16 MiB packed [x|h]
    unsigned short* WP = AP + 8388608;            //  3 MiB packed B-hat (R,U,C)

    cvt_all_kernel<<<4864, 256, 0, stream>>>(x, h, AP,
        Wx_r, Wh_r, Wx_u, Wh_u, Wx_h, Wh_h, WP);
    augru_mm<<<512, 512, 0, stream>>>(AP, WP, b_r, b_u, b_h, att, h, out);
}